// Round 7
// baseline (322.716 us; speedup 1.0000x reference)
//
#include <hip/hip_runtime.h>

typedef unsigned short u16;
typedef unsigned int   u32;
typedef __attribute__((ext_vector_type(4))) float  f32x4;
typedef __attribute__((ext_vector_type(8))) __bf16 bf16x8;

#define EMBED 2048
#define NH    16
#define NKV   4
#define HD    128
#define TT    2048
#define BB    2
#define MROWS (BB*TT)
#define QSCALE 0.08838834764831845f

#define QELEMS ((size_t)BB*NH*TT*HD)
#define KELEMS ((size_t)BB*NKV*TT*HD)

#define AS1(p) (__attribute__((address_space(1))) void*)(void*)(p)
#define AS3(p) (__attribute__((address_space(3))) void*)(void*)(p)

static __device__ __forceinline__ u16 f2b(float f){
  union { float f; u32 u; } v; v.f = f;
  u32 u = v.u;
  u32 r = u + 0x7FFFu + ((u >> 16) & 1u);   // RNE
  return (u16)(r >> 16);
}

// ---------------- fp32 -> bf16 convert (x) ----------------
__global__ __launch_bounds__(256) void cvt_f32_bf16(const float* __restrict__ in,
                                                    u16* __restrict__ out, int n4){
  int i = blockIdx.x * 256 + threadIdx.x;
  if (i >= n4) return;
  float4 v = ((const float4*)in)[i];
  uint2 o;
  o.x = (u32)f2b(v.x) | ((u32)f2b(v.y) << 16);
  o.y = (u32)f2b(v.z) | ((u32)f2b(v.w) << 16);
  ((uint2*)out)[i] = o;
}

// ---------------- fp32 [R][C] -> bf16 [C][R], two matrices per launch (z-dim) ----------------
__global__ __launch_bounds__(256) void trans_w2(const float* __restrict__ in0, u16* __restrict__ out0,
                                                const float* __restrict__ in1, u16* __restrict__ out1,
                                                int R, int C){
  const float* in = blockIdx.z ? in1 : in0;
  u16*        out = blockIdx.z ? out1 : out0;
  __shared__ u16 tile[32][33];
  int c0 = blockIdx.x * 32, r0 = blockIdx.y * 32;
  int tx = threadIdx.x & 31, ty = threadIdx.x >> 5;   // 32 x 8
  #pragma unroll
  for (int j = 0; j < 32; j += 8)
    tile[ty + j][tx] = f2b(in[(size_t)(r0 + ty + j) * C + c0 + tx]);
  __syncthreads();
  #pragma unroll
  for (int j = 0; j < 32; j += 8)
    out[(size_t)(c0 + ty + j) * R + r0 + tx] = tile[tx][ty + j];
}

// ---------------- bf16 [BH][T][D] -> [BH][D][T]  (V for PV fragment reads) ----------------
__global__ __launch_bounds__(256) void trans_v(const u16* __restrict__ in,
                                               u16* __restrict__ out){
  __shared__ u16 tile[32][33];
  int d0 = (blockIdx.x & 3) * 32;            // D/32 = 4
  int t0 = ((blockIdx.x >> 2) & 63) * 32;    // T/32 = 64
  int bh = blockIdx.x >> 8;                  // B*NKV = 8
  const u16* ip = in  + (size_t)bh * TT * HD;
  u16*       op = out + (size_t)bh * TT * HD;
  int tx = threadIdx.x & 31, ty = threadIdx.x >> 5;
  #pragma unroll
  for (int j = 0; j < 32; j += 8)
    tile[ty + j][tx] = ip[(size_t)(t0 + ty + j) * HD + d0 + tx];
  __syncthreads();
  #pragma unroll
  for (int j = 0; j < 32; j += 8)
    op[(size_t)(d0 + ty + j) * TT + t0 + tx] = tile[tx][ty + j];
}

// ---------------- 128^2 bf16 GEMM (m97 structure), EPI 0: fp32 out — used for O-projection ----
__global__ __launch_bounds__(256)
void gemm_bt(const u16* __restrict__ A, const u16* __restrict__ Bt,
             void* __restrict__ outp, int N, int K){
  __shared__ __align__(16) u16 As[2][128*32];
  __shared__ __align__(16) u16 Bs[2][128*32];
  int tid  = threadIdx.x;
  int lane = tid & 63, w = tid >> 6;
  int nwg = gridDim.x;
  int bid = blockIdx.x;
  bid = (bid & 7) * (nwg >> 3) + (bid >> 3);      // XCD swizzle (nwg % 8 == 0)
  int nbn  = N >> 7;
  int brow = (bid / nbn) * 128;
  int bcol = (bid % nbn) * 128;

  auto stage = [&](int buf, int kt){
    #pragma unroll
    for (int j = 0; j < 2; ++j){
      int boff  = w * 2048 + j * 1024;
      int chunk = (boff >> 4) + lane;
      int row   = chunk >> 2;
      int cko   = chunk & 3;
      const u16* ga = A  + (size_t)(brow + row) * K + kt + cko * 8;
      const u16* gb = Bt + (size_t)(bcol + row) * K + kt + cko * 8;
      __builtin_amdgcn_global_load_lds(AS1(ga), AS3(&As[buf][boff >> 1]), 16, 0, 0);
      __builtin_amdgcn_global_load_lds(AS1(gb), AS3(&Bs[buf][boff >> 1]), 16, 0, 0);
    }
  };

  int lr = lane & 15, lg = lane >> 4, lk = lg * 8;
  int wr = (w >> 1) * 64, wc = (w & 1) * 64;

  f32x4 acc[4][4];
  #pragma unroll
  for (int m = 0; m < 4; ++m)
    #pragma unroll
    for (int n = 0; n < 4; ++n)
      #pragma unroll
      for (int r = 0; r < 4; ++r) acc[m][n][r] = 0.f;

  int NT = K >> 5;
  stage(0, 0);
  asm volatile("s_waitcnt vmcnt(0)" ::: "memory");
  __syncthreads();
  int cur = 0;
  for (int t = 0; t < NT; ++t){
    if (t + 1 < NT) stage(cur ^ 1, (t + 1) * 32);
    const u16* as = As[cur];
    const u16* bs = Bs[cur];
    bf16x8 af[4], bfv[4];
    #pragma unroll
    for (int m = 0; m < 4; ++m) af[m]  = *(const bf16x8*)(as + (wr + m*16 + lr)*32 + lk);
    #pragma unroll
    for (int n = 0; n < 4; ++n) bfv[n] = *(const bf16x8*)(bs + (wc + n*16 + lr)*32 + lk);
    #pragma unroll
    for (int m = 0; m < 4; ++m)
      #pragma unroll
      for (int n = 0; n < 4; ++n)
        acc[m][n] = __builtin_amdgcn_mfma_f32_16x16x32_bf16(af[m], bfv[n], acc[m][n], 0, 0, 0);
    asm volatile("s_waitcnt vmcnt(0)" ::: "memory");
    __syncthreads();
    cur ^= 1;
  }

  float* o = (float*)outp;
  #pragma unroll
  for (int m = 0; m < 4; ++m)
    #pragma unroll
    for (int r = 0; r < 4; ++r){
      int rowg = brow + wr + m*16 + lg*4 + r;
      float* orow = o + (size_t)rowg * N + bcol + wc + lr;
      #pragma unroll
      for (int n = 0; n < 4; ++n) orow[n*16] = acc[m][n][r];
    }
}

// ---------------- 256x256, BK=64, 8-wave, 8-phase counted-vmcnt GEMM (T2+T3+T4+T5) ----------------
// C = A[M,K] * Bt[N,K]^T, fused QKV-split epilogue.
// LDS: As/Bs[2 dbuf][2 k-half][256 rows][32 k] — K-SPLIT halves so every wave's
//   phase->half mapping is uniform (phases 0,1 read k-half 0; phases 2,3 read k-half 1).
// Swizzle (both-sides, rule #21): 16B-chunk index within 64B row XOR'd with (row>>1)&3.
//   Read-side bank check: rows 0..15 x chunk' -> 8 distinct (row&1,chunk) slots x2 = 2-way (free).
// Stage schedule: phase p of tile t stages half H_p(t+1), H = [A0,B0,A1,B1].
// Gates (per-wave vmcnt BEFORE the trailing barrier => publication is block-wide sound):
//   end ph1: vmcnt(4) -> A1,B1(t) landed (outstanding then: A1,B1(t),A0,B0(t+1) = 8)
//   end ph3: vmcnt(4) -> A0,B0(t+1) landed (outstanding: 4 half-tiles of t+1 = 8)
// Never 0 mid-loop; tail drains.
__global__ __launch_bounds__(512, 2)
void gemm256_qkv(const u16* __restrict__ A, const u16* __restrict__ Bt,
                 u16* __restrict__ qkv, int N, int K){
  __shared__ __align__(16) u16 As[2][2][256*32];   // 64 KB
  __shared__ __align__(16) u16 Bs[2][2][256*32];   // 64 KB
  int tid = threadIdx.x, lane = tid & 63, w = tid >> 6;
  int nwg = gridDim.x, bid = blockIdx.x;
  bid = (bid & 7) * (nwg >> 3) + (bid >> 3);       // XCD swizzle (192 % 8 == 0)
  int nbn  = N >> 8;
  int brow = (bid / nbn) * 256;
  int bcol = (bid % nbn) * 256;
  int wm = w >> 2, wn = w & 3;                     // 2M x 4N wave grid
  int lr = lane & 15, lg = lane >> 4;
  int swz = (lg ^ ((lr >> 1) & 3)) << 3;           // element offset of this lane's 8-elem chunk

  auto stage = [&](const u16* __restrict__ src, u16* dst, int rowbase, int kt, int kk){
    #pragma unroll
    for (int j = 0; j < 2; ++j){
      int c = j * 512 + tid;                       // 16B-chunk id within 16KB half-tile
      int row = c >> 2, cc = c & 3;
      const u16* g = src + (size_t)(rowbase + row) * K + kt * 64 + kk * 32
                         + ((cc ^ ((row >> 1) & 3)) * 8);      // inverse swizzle on SOURCE
      __builtin_amdgcn_global_load_lds(AS1(g), AS3(dst + (j * 512 + w * 64) * 8), 16, 0, 0);
    }
  };

  f32x4 acc[8][4];
  #pragma unroll
  for (int m = 0; m < 8; ++m)
    #pragma unroll
    for (int n = 0; n < 4; ++n)
      #pragma unroll
      for (int r = 0; r < 4; ++r) acc[m][n][r] = 0.f;

  int NT = K >> 6;                                 // 32
  int arow = wm * 128 + lr;                        // + m*16, row stride 32 elems
  int brw  = wn * 64 + lr;                         // + n*16

  // prologue: stage tile 0 fully; wait for k-half 0 (A0,B0); A1,B1 stay in flight
  stage(A,  As[0][0], brow, 0, 0);
  stage(Bt, Bs[0][0], bcol, 0, 0);
  stage(A,  As[0][1], brow, 0, 1);
  stage(Bt, Bs[0][1], bcol, 0, 1);
  asm volatile("s_waitcnt vmcnt(4)" ::: "memory");
  __builtin_amdgcn_s_barrier();
  asm volatile("" ::: "memory");

  for (int t = 0; t < NT; ++t){
    int buf = t & 1, nb = buf ^ 1;
    bool pre = (t + 1 < NT);
    const u16* a0 = As[buf][0]; const u16* b0 = Bs[buf][0];
    const u16* a1 = As[buf][1]; const u16* b1 = Bs[buf][1];
    bf16x8 bfr[4], af[4];

    // ---- phase 0: k-half 0, m 0..3 ----
    #pragma unroll
    for (int n = 0; n < 4; ++n) bfr[n] = *(const bf16x8*)(b0 + (brw + n*16)*32 + swz);
    #pragma unroll
    for (int m = 0; m < 4; ++m) af[m]  = *(const bf16x8*)(a0 + (arow + m*16)*32 + swz);
    if (pre) stage(A, As[nb][0], brow, t + 1, 0);
    __builtin_amdgcn_s_barrier(); asm volatile("" ::: "memory");
    __builtin_amdgcn_s_setprio(1);
    #pragma unroll
    for (int m = 0; m < 4; ++m)
      #pragma unroll
      for (int n = 0; n < 4; ++n)
        acc[m][n] = __builtin_amdgcn_mfma_f32_16x16x32_bf16(af[m], bfr[n], acc[m][n], 0, 0, 0);
    __builtin_amdgcn_s_setprio(0);
    __builtin_amdgcn_s_barrier(); asm volatile("" ::: "memory");

    // ---- phase 1: k-half 0, m 4..7 (reuse bfr) ----
    #pragma unroll
    for (int m = 0; m < 4; ++m) af[m] = *(const bf16x8*)(a0 + (arow + (m+4)*16)*32 + swz);
    if (pre) stage(Bt, Bs[nb][0], bcol, t + 1, 0);
    __builtin_amdgcn_s_barrier(); asm volatile("" ::: "memory");
    __builtin_amdgcn_s_setprio(1);
    #pragma unroll
    for (int m = 0; m < 4; ++m)
      #pragma unroll
      for (int n = 0; n < 4; ++n)
        acc[m+4][n] = __builtin_amdgcn_mfma_f32_16x16x32_bf16(af[m], bfr[n], acc[m+4][n], 0, 0, 0);
    __builtin_amdgcn_s_setprio(0);
    if (pre) asm volatile("s_waitcnt vmcnt(4)" ::: "memory");   // A1,B1(t) published
    else     asm volatile("s_waitcnt vmcnt(0)" ::: "memory");   // tail drain
    __builtin_amdgcn_s_barrier(); asm volatile("" ::: "memory");

    // ---- phase 2: k-half 1, m 0..3 ----
    #pragma unroll
    for (int n = 0; n < 4; ++n) bfr[n] = *(const bf16x8*)(b1 + (brw + n*16)*32 + swz);
    #pragma unroll
    for (int m = 0; m < 4; ++m) af[m]  = *(const bf16x8*)(a1 + (arow + m*16)*32 + swz);
    if (pre) stage(A, As[nb][1], brow, t + 1, 1);
    __builtin_amdgcn_s_barrier(); asm volatile("" ::: "memory");
    __builtin_amdgcn_s_setprio(1);
    #pragma unroll
    for (int m = 0; m < 4; ++m)
      #pragma unroll
      for (int n = 0; n < 4; ++n)
        acc[m][n] = __builtin_amdgcn_mfma_f32_16x16x32_bf16(af[m], bfr[n], acc[m][n], 0, 0, 0);
    __builtin_amdgcn_s_setprio(0);
    __builtin_amdgcn_s_barrier(); asm volatile("" ::: "memory");

    // ---- phase 3: k-half 1, m 4..7 ----
    #pragma unroll
    for (int m = 0; m < 4; ++m) af[m] = *(const bf16x8*)(a1 + (arow + (m+4)*16)*32 + swz);
    if (pre) stage(Bt, Bs[nb][1], bcol, t + 1, 1);
    __builtin_amdgcn_s_barrier(); asm volatile("" ::: "memory");
    __builtin_amdgcn_s_setprio(1);
    #pragma unroll
    for (int m = 0; m < 4; ++m)
      #pragma unroll
      for (int n = 0; n < 4; ++n)
        acc[m+4][n] = __builtin_amdgcn_mfma_f32_16x16x32_bf16(af[m], bfr[n], acc[m+4][n], 0, 0, 0);
    __builtin_amdgcn_s_setprio(0);
    if (pre) asm volatile("s_waitcnt vmcnt(4)" ::: "memory");   // A0,B0(t+1) published
    __builtin_amdgcn_s_barrier(); asm volatile("" ::: "memory");
  }

  // ---- epilogue: route 64-col wave band to q / k / v (band is wave-uniform) ----
  u16* qb = qkv;
  u16* kb = qb + QELEMS;
  u16* vb = kb + KELEMS;
  int colbase = bcol + wn * 64;
  int hb = colbase >> 7;                 // 0..23
  int dbase = colbase & 127;
  int b = brow >> 11;                    // 256-row block never spans the b-boundary (2048|256)
  u16* hp; float s;
  if (hb < 16)      { hp = qb + ((size_t)(b*NH  +  hb     )) * TT * HD; s = QSCALE; }
  else if (hb < 20) { hp = kb + ((size_t)(b*NKV + (hb-16))) * TT * HD; s = 1.0f; }
  else              { hp = vb + ((size_t)(b*NKV + (hb-20))) * TT * HD; s = 1.0f; }
  #pragma unroll
  for (int m = 0; m < 8; ++m)
    #pragma unroll
    for (int r = 0; r < 4; ++r){
      int trow = (brow + wm*128 + m*16 + lg*4 + r) & (TT - 1);
      u16* orow = hp + (size_t)trow * HD + dbase + lr;
      #pragma unroll
      for (int n = 0; n < 4; ++n)
        orow[n*16] = f2b(acc[m][n][r] * s);
    }
}

// ---------------- flash attention: LDS-staged K/V (XOR-swizzled), paired q-tiles ----------------
__global__ __launch_bounds__(256)
void attn_kernel(const u16* __restrict__ qb, const u16* __restrict__ kb,
                 const u16* __restrict__ vtb, u16* __restrict__ ob){
  __shared__ __align__(16) u16 Ks[2][64*128];   // [kv 64][d 128], chunk-swizzled
  __shared__ __align__(16) u16 Vs[2][128*64];   // [d 128][kv 64], chunk-swizzled
  __shared__ __align__(16) u16 pl[4][16*88];    // per-wave P scratch, stride 88
  int tid = threadIdx.x, lane = tid & 63, w = tid >> 6;
  int nwg = gridDim.x;                          // 512
  int bid = blockIdx.x;
  bid = (bid & 7) * (nwg >> 3) + (bid >> 3);    // chunked XCD swizzle
  int pair = bid & 15;
  int h    = (bid >> 4) & 15;
  int b    = bid >> 8;
  int hkv  = h >> 2;
  int lr = lane & 15, lg = lane >> 4, lk = lg * 8;
  int sw = (lr & 7) << 3;

  const u16* qbase = qb  + ((size_t)b * NH  + h  ) * TT * HD;
  const u16* kbase = kb  + ((size_t)b * NKV + hkv) * TT * HD;
  const u16* vbase = vtb + ((size_t)b * NKV + hkv) * HD * TT;

  auto stage = [&](int buf, int kt){
    #pragma unroll
    for (int i = 0; i < 4; ++i){
      int c  = i * 256 + tid;
      int ub = (i * 256 + w * 64) * 8;
      int kr = c >> 4, kc = (c & 15) ^ (kr & 7);
      const u16* gk = kbase + (size_t)(kt * 64 + kr) * HD + kc * 8;
      __builtin_amdgcn_global_load_lds(AS1(gk), AS3(&Ks[buf][ub]), 16, 0, 0);
      int vr = c >> 3, vc = (c & 7) ^ (vr & 7);
      const u16* gv = vbase + (size_t)vr * TT + kt * 64 + vc * 8;
      __builtin_amdgcn_global_load_lds(AS1(gv), AS3(&Vs[buf][ub]), 16, 0, 0);
    }
  };

  __bf16* plw = (__bf16*)pl[w];

  for (int half = 0; half < 2; ++half){
    int qt = half ? (31 - pair) : pair;
    int q0 = qt * 64 + w * 16;

    bf16x8 aq[4];
    #pragma unroll
    for (int s = 0; s < 4; ++s)
      aq[s] = *(const bf16x8*)(qbase + (size_t)(q0 + lr) * HD + s*32 + lk);

    f32x4 o_acc[8];
    #pragma unroll
    for (int dt = 0; dt < 8; ++dt)
      #pragma unroll
      for (int r = 0; r < 4; ++r) o_acc[dt][r] = 0.f;
    float mrow[4], lrow[4];
    #pragma unroll
    for (int r = 0; r < 4; ++r){ mrow[r] = -1e30f; lrow[r] = 0.f; }

    __builtin_amdgcn_s_barrier();
    stage(0, 0);
    int cur = 0;
    for (int kt = 0; kt <= qt; ++kt){
      __builtin_amdgcn_s_barrier();
      if (kt < qt){
        stage(cur ^ 1, kt + 1);
        asm volatile("s_waitcnt vmcnt(8)" ::: "memory");
      } else {
        asm volatile("s_waitcnt vmcnt(0)" ::: "memory");
      }
      __builtin_amdgcn_s_barrier();

      const u16* ks = Ks[cur];
      f32x4 sc[4];
      #pragma unroll
      for (int c = 0; c < 4; ++c)
        #pragma unroll
        for (int r = 0; r < 4; ++r) sc[c][r] = 0.f;
      __builtin_amdgcn_s_setprio(1);
      #pragma unroll
      for (int c = 0; c < 4; ++c){
        const u16* kp = ks + (c*16 + lr) * 128;
        #pragma unroll
        for (int s = 0; s < 4; ++s){
          bf16x8 kf = *(const bf16x8*)(kp + (((s*32) + lk) ^ sw));
          sc[c] = __builtin_amdgcn_mfma_f32_16x16x32_bf16(aq[s], kf, sc[c], 0, 0, 0);
        }
      }
      __builtin_amdgcn_s_setprio(0);
      if (kt == qt){
        #pragma unroll
        for (int c = 0; c < 4; ++c){
          int kvg = kt*64 + c*16 + lr;
          #pragma unroll
          for (int r = 0; r < 4; ++r){
            int qg = q0 + lg*4 + r;
            if (kvg > qg) sc[c][r] = -1e30f;
          }
        }
      }
      float tmv[4];
      #pragma unroll
      for (int r = 0; r < 4; ++r){
        float tm = fmaxf(fmaxf(sc[0][r], sc[1][r]), fmaxf(sc[2][r], sc[3][r]));
        tm = fmaxf(tm, __shfl_xor(tm, 1));
        tm = fmaxf(tm, __shfl_xor(tm, 2));
        tm = fmaxf(tm, __shfl_xor(tm, 4));
        tm = fmaxf(tm, __shfl_xor(tm, 8));
        tmv[r] = tm;
      }
      bool need = (tmv[0] > mrow[0] + 8.f) || (tmv[1] > mrow[1] + 8.f) ||
                  (tmv[2] > mrow[2] + 8.f) || (tmv[3] > mrow[3] + 8.f);
      if (__any(need ? 1 : 0)){
        #pragma unroll
        for (int r = 0; r < 4; ++r){
          float mnew  = fmaxf(mrow[r], tmv[r]);
          float alpha = __expf(mrow[r] - mnew);
          mrow[r] = mnew;
          lrow[r] *= alpha;
          #pragma unroll
          for (int dt = 0; dt < 8; ++dt) o_acc[dt][r] *= alpha;
        }
      }
      #pragma unroll
      for (int r = 0; r < 4; ++r){
        float rs = 0.f;
        #pragma unroll
        for (int c = 0; c < 4; ++c){
          float p = __expf(sc[c][r] - mrow[r]);
          rs += p;
          plw[(lg*4 + r)*88 + c*16 + lr] = (__bf16)p;
        }
        rs += __shfl_xor(rs, 1); rs += __shfl_xor(rs, 2);
        rs += __shfl_xor(rs, 4); rs += __shfl_xor(rs, 8);
        lrow[r] += rs;
      }
      asm volatile("s_waitcnt lgkmcnt(0)" ::: "memory");
      bf16x8 pa[2];
      #pragma unroll
      for (int kk = 0; kk < 2; ++kk)
        pa[kk] = *(const bf16x8*)((const u16*)plw + lr*88 + kk*32 + lk);
      const u16* vs = Vs[cur];
      __builtin_amdgcn_s_setprio(1);
      #pragma unroll
      for (int dt = 0; dt < 8; ++dt){
        const u16* vp = vs + (dt*16 + lr) * 64;
        #pragma unroll
        for (int kk = 0; kk < 2; ++kk){
          bf16x8 vf = *(const bf16x8*)(vp + (((kk*32) + lk) ^ sw));
          o_acc[dt] = __builtin_amdgcn_mfma_f32_16x16x32_bf16(pa[kk], vf, o_acc[dt], 0, 0, 0);
        }
      }
      __builtin_amdgcn_s_setprio(0);
      cur ^= 1;
    }
    #pragma unroll
    for (int r = 0; r < 4; ++r){
      float inv = 1.0f / lrow[r];
      int t = q0 + lg*4 + r;
      size_t base = ((size_t)b * TT + t) * EMBED + h * HD;
      #pragma unroll
      for (int dt = 0; dt < 8; ++dt)
        ob[base + dt*16 + lr] = f2b(o_acc[dt][r] * inv);
    }
  }
}

extern "C" void kernel_launch(void* const* d_in, const int* in_sizes, int n_in,
                              void* d_out, int out_size, void* d_ws, size_t ws_size,
                              hipStream_t stream){
  const float* x  = (const float*)d_in[0];
  const float* Wq = (const float*)d_in[1];
  const float* Wk = (const float*)d_in[2];
  const float* Wv = (const float*)d_in[3];
  const float* Wo = (const float*)d_in[4];

  char* ws = (char*)d_ws;
  size_t off = 0;
  auto alloc = [&](size_t bytes){ void* p = ws + off; off += (bytes + 255) & ~(size_t)255; return p; };
  u16* xb    = (u16*)alloc((size_t)MROWS * EMBED * 2);
  u16* Wqkvt = (u16*)alloc((size_t)3072 * EMBED * 2);        // rows: 0..2047 Wq, 2048..2559 Wk, 2560..3071 Wv
  u16* Wot   = (u16*)alloc((size_t)EMBED * EMBED * 2);
  u16* qkv   = (u16*)alloc((QELEMS + 2*KELEMS) * 2);          // q | k | v contiguous
  u16* vtb   = (u16*)alloc(KELEMS * 2);
  u16* ob    = (u16*)alloc((size_t)MROWS * EMBED * 2);

  u16* qb = qkv;
  u16* kb = qb + QELEMS;
  u16* vb = kb + KELEMS;

  cvt_f32_bf16<<<(MROWS*EMBED/4 + 255)/256, 256, 0, stream>>>(x, xb, MROWS*EMBED/4);
  trans_w2<<<dim3(EMBED/32, EMBED/32, 2), 256, 0, stream>>>(Wq, Wqkvt, Wo, Wot, EMBED, EMBED);
  trans_w2<<<dim3(512/32,   EMBED/32, 2), 256, 0, stream>>>(Wk, Wqkvt + (size_t)2048*EMBED,
                                                            Wv, Wqkvt + (size_t)2560*EMBED, EMBED, 512);

  gemm256_qkv<<<(MROWS/256)*(3072/256), 512, 0, stream>>>(xb, Wqkvt, qkv, 3072, EMBED);
  trans_v<<<4*64*BB*NKV, 256, 0, stream>>>(vb, vtb);

  attn_kernel<<<BB*NH*16, 256, 0, stream>>>(qb, kb, vtb, ob);

  gemm_bt<<<(MROWS/128)*(EMBED/128), 256, 0, stream>>>(ob, Wot, d_out, EMBED, EMBED);
}